// Round 2
// baseline (611.080 us; speedup 1.0000x reference)
//
#include <hip/hip_runtime.h>

#define S_LEN 2048
#define D_DIM 1024

// ============================ Phase 1 ============================
// Fused GEMM: [32 tokens x 1024] x [1024 x 140(pad 160)] -> feats/sel/comb,
// then per-token: softmax(sel) -> probs, C=sum_m p_m T_m, t=C@feat.
// Grid: 256 WGs x 256 threads, 32 tokens/WG.
// Thread (cg 0..31, tg 0..7): 4 tokens x 5 cols register tile.
#define P1_KC 128
#define P1_XSTR 36     // 32 tokens + pad (bank spread, keeps 16B align)
#define P1_OSTR 164    // 160 cols + pad 4

__global__ __launch_bounds__(256) void lap_phase1(
    const float* __restrict__ x,
    const float* __restrict__ gen_w, const float* __restrict__ gen_b,
    const float* __restrict__ sel_w, const float* __restrict__ sel_b,
    const float* __restrict__ templates,
    const float* __restrict__ comb_w, const float* __restrict__ comb_b,
    float* __restrict__ kf, float* __restrict__ tv, float* __restrict__ combo)
{
    __shared__ float xs[P1_KC][P1_XSTR];
    __shared__ float outs[32][P1_OSTR];

    const int tid = threadIdx.x;
    const int tok0 = blockIdx.x * 32;
    const int cg = tid & 31;
    const int tg = tid >> 5;

    // per-thread weight-row pointers for 5 columns (cols >=140 are unused pad)
    const float* wp[5];
    float bias5[5];
#pragma unroll
    for (int cc = 0; cc < 5; ++cc) {
        int col = cg * 5 + cc;
        if (col < 128)      { wp[cc] = gen_w  + (size_t)col * D_DIM;       bias5[cc] = gen_b[col]; }
        else if (col < 136) { wp[cc] = sel_w  + (size_t)(col-128) * D_DIM; bias5[cc] = sel_b[col-128]; }
        else if (col < 140) { wp[cc] = comb_w + (size_t)(col-136) * D_DIM; bias5[cc] = comb_b[col-136]; }
        else                { wp[cc] = sel_w;                              bias5[cc] = 0.0f; }
    }

    float acc[4][5];
#pragma unroll
    for (int r = 0; r < 4; ++r)
#pragma unroll
        for (int cc = 0; cc < 5; ++cc) acc[r][cc] = bias5[cc];  // bias folded into init

    for (int k0 = 0; k0 < D_DIM; k0 += P1_KC) {
        __syncthreads();
        {   // stage x[32 tok][128 k] transposed into xs[k][tok]
            const int ltok = tid >> 3;   // 0..31
            const int kq   = tid & 7;    // 0..7
            const float4* xp = (const float4*)(x + (size_t)(tok0 + ltok) * D_DIM + k0);
#pragma unroll
            for (int j = 0; j < 4; ++j) {
                float4 v = xp[kq + 8*j];
                int kk = (kq + 8*j) * 4;
                xs[kk+0][ltok] = v.x; xs[kk+1][ltok] = v.y;
                xs[kk+2][ltok] = v.z; xs[kk+3][ltok] = v.w;
            }
        }
        __syncthreads();
#pragma unroll 4
        for (int kk = 0; kk < P1_KC; ++kk) {
            const float4 xv = *(const float4*)&xs[kk][tg*4];
            float wv[5];
#pragma unroll
            for (int cc = 0; cc < 5; ++cc) wv[cc] = wp[cc][k0+kk];
#pragma unroll
            for (int cc = 0; cc < 5; ++cc) {
                acc[0][cc] += xv.x * wv[cc];
                acc[1][cc] += xv.y * wv[cc];
                acc[2][cc] += xv.z * wv[cc];
                acc[3][cc] += xv.w * wv[cc];
            }
        }
    }

#pragma unroll
    for (int r = 0; r < 4; ++r)
#pragma unroll
        for (int cc = 0; cc < 5; ++cc) outs[tg*4+r][cg*5+cc] = acc[r][cc];
    __syncthreads();

    // -------- epilogue: probs, comb, C, t, stores --------
    const int ig  = tid >> 5;   // 0..7 -> 4 pattern rows each
    const int ltk = tid & 31;   // token within tile
    const size_t token = (size_t)tok0 + ltk;

    float p[8];
    {
        float lg[8];
#pragma unroll
        for (int mI = 0; mI < 8; ++mI) lg[mI] = outs[ltk][128+mI];
        float mx = lg[0];
#pragma unroll
        for (int mI = 1; mI < 8; ++mI) mx = fmaxf(mx, lg[mI]);
        float sum = 0.f;
#pragma unroll
        for (int mI = 0; mI < 8; ++mI) { p[mI] = __expf(lg[mI]-mx); sum += p[mI]; }
        float inv = 1.0f / sum;
#pragma unroll
        for (int mI = 0; mI < 8; ++mI) p[mI] *= inv;
    }

    if (ig == 0) {
#pragma unroll
        for (int hh = 0; hh < 4; ++hh) combo[token*4+hh] = outs[ltk][136+hh];
    }

#pragma unroll 1
    for (int r = 0; r < 4; ++r) {
        const int i = ig*4 + r;
        float crow[32];
#pragma unroll
        for (int j = 0; j < 32; ++j) crow[j] = 0.f;
#pragma unroll
        for (int mI = 0; mI < 8; ++mI) {
            const float4* Tp = (const float4*)(templates + ((size_t)mI*32 + i)*32);
            const float pm = p[mI];
#pragma unroll
            for (int j4 = 0; j4 < 8; ++j4) {
                float4 t4 = Tp[j4];
                crow[j4*4+0] += pm*t4.x; crow[j4*4+1] += pm*t4.y;
                crow[j4*4+2] += pm*t4.z; crow[j4*4+3] += pm*t4.w;
            }
        }
#pragma unroll
        for (int hh = 0; hh < 4; ++hh) {
            float s = 0.f;
#pragma unroll
            for (int j4 = 0; j4 < 8; ++j4) {
                float4 f4 = *(const float4*)&outs[ltk][hh*32 + j4*4];
                s += crow[j4*4+0]*f4.x + crow[j4*4+1]*f4.y
                   + crow[j4*4+2]*f4.z + crow[j4*4+3]*f4.w;
            }
            tv[token*128 + hh*32 + i] = s;
        }
    }

    // kf (feats incl. bias), coalesced float4 store
#pragma unroll
    for (int pp = 0; pp < 4; ++pp) {
        int tk = (tid >> 5) + 8*pp;
        int j4 = tid & 31;
        float4 v = *(const float4*)&outs[tk][j4*4];
        *(float4*)&kf[((size_t)tok0 + tk)*128 + j4*4] = v;
    }
}

// ============================ Phase 2 ============================
// Per WG: one batch b, 16 query rows. Wave = head. Lane (qg,sg): 4 q-rows
// register-blocked, key slots s = 16*it + sg. Two-pass causal softmax:
// Pass A online (m,Z) + 16-lane butterfly reduce; Pass B recompute -> LDS
// head-combine tile -> coalesced float4 writes; explicit zero-fill.
__global__ __launch_bounds__(256, 2) void lap_phase2(
    const float* __restrict__ kf, const float* __restrict__ tv,
    const float* __restrict__ combo, float* __restrict__ out)
{
    __shared__ float sc[4][16][68];

    const int tid  = threadIdx.x;
    const int wgid = blockIdx.x;
    const int b  = wgid & 3;
    const int qt = 127 - (wgid >> 2);   // heavy tiles dispatched first (LPT)
    const int q0 = qt * 16;

    const int h  = tid >> 6;
    const int l  = tid & 63;
    const int qg = l >> 4;
    const int sg = l & 15;
    const int qbase = q0 + qg*4;

    const float* kfb = kf + (size_t)b * S_LEN * 128;

    float4 treg[4][8];
#pragma unroll
    for (int r = 0; r < 4; ++r) {
        const float4* tp = (const float4*)(tv + ((size_t)(b*S_LEN) + qbase + r)*128 + h*32);
#pragma unroll
        for (int j4 = 0; j4 < 8; ++j4) treg[r][j4] = tp[j4];
    }

    float m[4], Z[4];
#pragma unroll
    for (int r = 0; r < 4; ++r) { m[r] = -1e30f; Z[r] = 0.f; }

    // ---- Pass A: online max/denominator ----
    const int nIt = qt + 1;
    for (int it = 0; it < nIt; ++it) {
        const int s = it*16 + sg;
        const float4* kp = (const float4*)(kfb + (size_t)s*128 + h*32);
        float4 kreg[8];
#pragma unroll
        for (int j4 = 0; j4 < 8; ++j4) kreg[j4] = kp[j4];
#pragma unroll
        for (int r = 0; r < 4; ++r) {
            float sco = 0.f;
#pragma unroll
            for (int j4 = 0; j4 < 8; ++j4) {
                sco += kreg[j4].x*treg[r][j4].x + kreg[j4].y*treg[r][j4].y
                     + kreg[j4].z*treg[r][j4].z + kreg[j4].w*treg[r][j4].w;
            }
            if (s <= qbase + r) {
                if (sco > m[r]) { Z[r] = Z[r]*__expf(m[r]-sco) + 1.0f; m[r] = sco; }
                else            { Z[r] += __expf(sco - m[r]); }
            }
        }
    }

    // butterfly reduce (m,Z) across the 16 key-slot lanes
#pragma unroll
    for (int r = 0; r < 4; ++r) {
#pragma unroll
        for (int w = 1; w < 16; w <<= 1) {
            float mo = __shfl_xor(m[r], w, 64);
            float Zo = __shfl_xor(Z[r], w, 64);
            float mn = fmaxf(m[r], mo);
            Z[r] = Z[r]*__expf(m[r]-mn) + Zo*__expf(mo-mn);
            m[r] = mn;
        }
    }

    float cz[4];
#pragma unroll
    for (int r = 0; r < 4; ++r)
        cz[r] = combo[((size_t)(b*S_LEN) + qbase + r)*4 + h] / Z[r];

    const int qq = tid >> 4;
    const int sp = tid & 15;
    float* outRow = out + ((size_t)(b*S_LEN) + q0 + qq) * S_LEN;

    // ---- Pass B: recompute, combine heads, write ----
    const int nTile = (q0 + 16 + 63) >> 6;
    for (int ts = 0; ts < nTile; ++ts) {
        const int s0 = ts * 64;
#pragma unroll
        for (int it2 = 0; it2 < 4; ++it2) {
            const int s = s0 + it2*16 + sg;
            const float4* kp = (const float4*)(kfb + (size_t)s*128 + h*32);
            float4 kreg[8];
#pragma unroll
            for (int j4 = 0; j4 < 8; ++j4) kreg[j4] = kp[j4];
#pragma unroll
            for (int r = 0; r < 4; ++r) {
                float sco = 0.f;
#pragma unroll
                for (int j4 = 0; j4 < 8; ++j4) {
                    sco += kreg[j4].x*treg[r][j4].x + kreg[j4].y*treg[r][j4].y
                         + kreg[j4].z*treg[r][j4].z + kreg[j4].w*treg[r][j4].w;
                }
                float val = (s <= qbase + r) ? __expf(sco - m[r]) * cz[r] : 0.0f;
                sc[h][qg*4+r][it2*16+sg] = val;
            }
        }
        __syncthreads();
        {
            float4 a; a.x = a.y = a.z = a.w = 0.f;
#pragma unroll
            for (int hh = 0; hh < 4; ++hh) {
                const float4 v = *(const float4*)&sc[hh][qq][sp*4];
                a.x += v.x; a.y += v.y; a.z += v.z; a.w += v.w;
            }
            *(float4*)&outRow[s0 + sp*4] = a;
        }
        __syncthreads();
    }

    // zero-fill the strictly-masked tail [nTile*64, S)
    {
        float4 z4; z4.x = z4.y = z4.z = z4.w = 0.f;
        for (int s = nTile*64 + sp*4; s < S_LEN; s += 64)
            *(float4*)&outRow[s] = z4;
    }
}

// ============================ launch ============================
extern "C" void kernel_launch(void* const* d_in, const int* in_sizes, int n_in,
                              void* d_out, int out_size, void* d_ws, size_t ws_size,
                              hipStream_t stream) {
    const float* x         = (const float*)d_in[0];
    const float* gen_w     = (const float*)d_in[1];
    const float* gen_b     = (const float*)d_in[2];
    const float* sel_w     = (const float*)d_in[3];
    const float* sel_b     = (const float*)d_in[4];
    const float* templates = (const float*)d_in[5];
    const float* comb_w    = (const float*)d_in[6];
    const float* comb_b    = (const float*)d_in[7];

    float* ws = (float*)d_ws;
    float* kf    = ws;                 // [4*2048][128]  feats (bias incl.)
    float* tv    = ws + 1048576;       // [4*2048][128]  t = C @ feat
    float* combo = ws + 2097152;       // [4*2048][4]    comb weights

    lap_phase1<<<256, 256, 0, stream>>>(x, gen_w, gen_b, sel_w, sel_b,
                                        templates, comb_w, comb_b,
                                        kf, tv, combo);
    lap_phase2<<<512, 256, 0, stream>>>(kf, tv, combo, (float*)d_out);
}